// Round 3
// baseline (491.914 us; speedup 1.0000x reference)
//
#include <hip/hip_runtime.h>
#include <hip/hip_bf16.h>
#include <cstdint>
#include <cmath>

typedef __attribute__((ext_vector_type(4))) float f32x4;
typedef __attribute__((ext_vector_type(8))) short bf16x8;

#define BAR()   __builtin_amdgcn_s_barrier()
#define PRIO1() __builtin_amdgcn_s_setprio(1)
#define PRIO0() __builtin_amdgcn_s_setprio(0)
#define WAITV4() asm volatile("s_waitcnt vmcnt(4)" ::: "memory")
#define WAITV0() asm volatile("s_waitcnt vmcnt(0)" ::: "memory")
#define MM(a,b,c) __builtin_amdgcn_mfma_f32_16x16x32_bf16((a),(b),(c),0,0,0)

__device__ __forceinline__ void gl_lds16(const __hip_bfloat16* g, char* l) {
    __builtin_amdgcn_global_load_lds(
        (const __attribute__((address_space(1))) void*)g,
        (__attribute__((address_space(3))) void*)l, 16, 0, 0);
}
__device__ __forceinline__ void store_c(float* C, size_t i, float v) { C[i] = v; }
__device__ __forceinline__ void store_c(__hip_bfloat16* C, size_t i, float v) { C[i] = __float2bfloat16(v); }

// ---------------------------------------------------------------------------
// 256x256-tile GEMM, BK=32, 8 waves (2Mx4N, wave tile 128x64), 3-buffer LDS
// (96KB) with 2-tile-deep prefetch: tile t's stages issued during tile t-2,
// boundary wait = counted vmcnt(4) (tile t+1's 4 loads stay in flight).
// Per tile: 3 barriers, 12 ds_read_b128, 4 global_load_lds, 32 MFMA/wave.
// LDS tile layout: 16 subtiles (16 rows x 32 cols bf16 = 1024B), inner byte
// (r&15)*64 + c*2 XOR-swizzled bit5 ^= bit9 (bank-conflict-free, R1-proven).
// Staging: linear global_load_lds dest, inverse-swizzled per-lane global src.
// CSKIP: skip blocks strictly above causal diagonal. KLIM: kend = bm0+256.
// ---------------------------------------------------------------------------
#define STAGEA(nb, kt) do{ gl_lds16(Asrc + (kt),                        lds + (nb)         + wb); \
                           gl_lds16(Asrc + (size_t)128 * lda + (kt),    lds + (nb) +  8192 + wb);}while(0)
#define STAGEB(nb, kt) do{ gl_lds16(Bsrc + (kt),                        lds + (nb) + 16384 + wb); \
                           gl_lds16(Bsrc + (size_t)128 * ldb + (kt),    lds + (nb) + 24576 + wb);}while(0)

template<typename CT, bool CSKIP, bool KLIM>
__global__ __launch_bounds__(512, 2)
void gemm256(const __hip_bfloat16* __restrict__ A, const __hip_bfloat16* __restrict__ B,
             CT* __restrict__ C, int K, int lda, int ldb, int ldc, int nbx,
             float alpha, size_t sA, size_t sB, size_t sC)
{
    __shared__ __align__(1024) char lds[98304];

    // bijective XCD-aware swizzle (m204)
    const int nwg = gridDim.x;
    const int q8 = nwg >> 3, r8 = nwg & 7;
    const int xcd = blockIdx.x & 7, blk = blockIdx.x >> 3;
    const int wg = (xcd < r8 ? xcd * (q8 + 1) : r8 * (q8 + 1) + (xcd - r8) * q8) + blk;
    const int bx = wg % nbx, by = wg / nbx;
    const int bm0 = by * 256, bn0 = bx * 256;
    if (CSKIP && bn0 >= bm0 + 256) return;

    A += sA * blockIdx.y; B += sB * blockIdx.y; C += sC * blockIdx.y;

    const int tid  = threadIdx.x;
    const int lane = tid & 63;
    const int w    = tid >> 6;
    const int wb   = w * 1024;

    // ds_read per-lane swizzled inner offset (fr = lane&15, k-sub = lane>>4)
    const int rb   = (lane & 15) * 64 + (lane >> 4) * 16;
    const int rswz = rb ^ (((rb >> 9) & 1) << 5);
    const int srA  = (w >> 2) * 8;      // A subtile base; +mi
    const int srB  = (w & 3) * 4;       // B subtile base; +ni

    // staging: invert swizzled layout for this thread's linear LDS chunk
    const int q0 = tid * 16;
    const int uq = q0 ^ (((q0 >> 9) & 1) << 5);
    const int r0 = ((q0 >> 10) << 4) | ((uq >> 6) & 15);
    const int c0 = (uq & 63) >> 1;
    const __hip_bfloat16* Asrc = A + (size_t)(bm0 + r0) * lda + c0;
    const __hip_bfloat16* Bsrc = B + (size_t)(bn0 + r0) * ldb + c0;

    f32x4 acc[8][4] = {};
    bf16x8 af[4], bf[4];

    const int klim = bm0 + 256;
    const int kend = KLIM ? (K < klim ? K : klim) : K;
    const int nt   = kend >> 5;

    // prologue: tile0 -> buf0, tile1 -> buf1
    STAGEA(0, 0); STAGEB(0, 0);
    if (nt > 1) { STAGEA(32768, 32); STAGEB(32768, 32); }

    for (int t = 0; t < nt; ++t) {
        if (t + 1 < nt) WAITV4(); else WAITV0();
        BAR();
        const char* dA = lds + (t % 3) * 32768;
        const char* dB = dA + 16384;
        const int  nbo = ((t + 2) % 3) * 32768;
        const bool pf  = (t + 2 < nt);
        const int  kt  = (t + 2) << 5;

        // ---- phase 0: A mi0-3 + B all; MFMA upper half ----
#pragma unroll
        for (int i = 0; i < 4; ++i) af[i] = *(const bf16x8*)(dA + ((srA + i) << 10) + rswz);
#pragma unroll
        for (int i = 0; i < 4; ++i) bf[i] = *(const bf16x8*)(dB + ((srB + i) << 10) + rswz);
        if (pf) STAGEA(nbo, kt);
        BAR();
        PRIO1();
#pragma unroll
        for (int mi = 0; mi < 4; ++mi)
#pragma unroll
            for (int ni = 0; ni < 4; ++ni)
                acc[mi][ni] = MM(af[mi], bf[ni], acc[mi][ni]);
        PRIO0();

        // ---- phase 1: A mi4-7 (B reused); MFMA lower half ----
#pragma unroll
        for (int i = 0; i < 4; ++i) af[i] = *(const bf16x8*)(dA + ((srA + 4 + i) << 10) + rswz);
        if (pf) STAGEB(nbo, kt);
        BAR();
        PRIO1();
#pragma unroll
        for (int mi = 0; mi < 4; ++mi)
#pragma unroll
            for (int ni = 0; ni < 4; ++ni)
                acc[4 + mi][ni] = MM(af[mi], bf[ni], acc[4 + mi][ni]);
        PRIO0();
    }

    // epilogue: C/D layout col=lane&15, row=(lane>>4)*4+j (m89/m91)
    const int cr = (lane >> 4) * 4, cc = lane & 15;
    const int wrow = bm0 + (w >> 2) * 128, wcol = bn0 + (w & 3) * 64;
#pragma unroll
    for (int mi = 0; mi < 8; ++mi)
#pragma unroll
        for (int ni = 0; ni < 4; ++ni) {
            const int row = wrow + mi * 16 + cr;
            const int col = wcol + ni * 16 + cc;
#pragma unroll
            for (int j = 0; j < 4; ++j)
                store_c(C, (size_t)(row + j) * ldc + col, acc[mi][ni][j] * alpha);
        }
}

// ---------------------------------------------------------------------------
__global__ void f32_to_bf16_vec(const float* __restrict__ in,
                                __hip_bfloat16* __restrict__ out, int n4)
{
    int i = blockIdx.x * 256 + threadIdx.x;
    if (i >= n4) return;
    float4 v = ((const float4*)in)[i];
    union { ushort4 u; __hip_bfloat16 h[4]; } o;
    o.h[0] = __float2bfloat16(v.x);
    o.h[1] = __float2bfloat16(v.y);
    o.h[2] = __float2bfloat16(v.z);
    o.h[3] = __float2bfloat16(v.w);
    ((ushort4*)out)[i] = o.u;
}

// 4 same-size weight matrices in one dispatch (blockIdx.y selects)
__global__ void conv_w4(const float* __restrict__ w0, const float* __restrict__ w1,
                        const float* __restrict__ w2, const float* __restrict__ w3,
                        __hip_bfloat16* o0, __hip_bfloat16* o1,
                        __hip_bfloat16* o2, __hip_bfloat16* o3, int n4)
{
    int i = blockIdx.x * 256 + threadIdx.x;
    if (i >= n4) return;
    const float* src; __hip_bfloat16* dst;
    switch (blockIdx.y) {
        case 0: src = w0; dst = o0; break;
        case 1: src = w1; dst = o1; break;
        case 2: src = w2; dst = o2; break;
        default: src = w3; dst = o3; break;
    }
    float4 v = ((const float4*)src)[i];
    union { ushort4 u; __hip_bfloat16 h[4]; } o;
    o.h[0] = __float2bfloat16(v.x);
    o.h[1] = __float2bfloat16(v.y);
    o.h[2] = __float2bfloat16(v.z);
    o.h[3] = __float2bfloat16(v.w);
    ((ushort4*)dst)[i] = o.u;
}

__global__ void rope_table(const int* __restrict__ pos, float2* __restrict__ tab, int N)
{
    int i = blockIdx.x * 256 + threadIdx.x;
    if (i >= N * 64) return;
    int n = i >> 6, j = i & 63;
    float p = (float)pos[n];
    float ang = p * powf(10000.f, -(float)j * (1.0f / 64.0f));
    tab[i] = make_float2(cosf(ang), sinf(ang));
}

// RoPE on Q and K in one dispatch, 16B vectorized (4 interleaved pairs/thread)
__global__ void rope_apply2(__hip_bfloat16* __restrict__ Q, __hip_bfloat16* __restrict__ K,
                            const float2* __restrict__ tab)
{
    int i = blockIdx.x * 256 + threadIdx.x;     // 8192 rows x 256 chunks
    __hip_bfloat16* T = blockIdx.y ? K : Q;
    int r  = i >> 8;
    int cb = (i & 255) << 3;                    // col base: 8 cols = 4 pairs
    int n  = r & 2047;
    int j0 = (cb >> 1) & 63;                    // pair idx within head (no wrap: j0%4==0)
    union { bf16x8 v; __hip_bfloat162 h[4]; } u;
    __hip_bfloat16* p = T + ((size_t)r << 11) + cb;
    u.v = *(const bf16x8*)p;
#pragma unroll
    for (int k = 0; k < 4; ++k) {
        float2 cs = tab[(n << 6) + j0 + k];
        float x1 = __bfloat162float(u.h[k].x);
        float x2 = __bfloat162float(u.h[k].y);
        u.h[k].x = __float2bfloat16(cs.x * x1 - cs.y * x2);
        u.h[k].y = __float2bfloat16(cs.y * x1 + cs.x * x2);
    }
    *(bf16x8*)p = u.v;
}

// ---------------------------------------------------------------------------
// In-place causal softmax: fp32 row q of S -> bf16 P over the same row
// (row stride stays 8KB = 4096 bf16 elements). Row staged in LDS.
// ---------------------------------------------------------------------------
__global__ void softmax_causal_ip(float* __restrict__ S, int N)
{
    const int q = blockIdx.x;
    float* srow = S + ((size_t)blockIdx.y * N + q) * N;
    __shared__ float buf[2048];
    __shared__ float red[8];
    const int tid = threadIdx.x;

    float4* b4 = (float4*)buf;
    const float4* s4 = (const float4*)srow;
    for (int i = tid; i < N / 4; i += 256) b4[i] = s4[i];
    __syncthreads();

    float m = -1e30f;
    for (int j = tid; j <= q; j += 256) m = fmaxf(m, buf[j]);
#pragma unroll
    for (int o = 32; o > 0; o >>= 1) m = fmaxf(m, __shfl_xor(m, o));
    if ((tid & 63) == 0) red[tid >> 6] = m;
    __syncthreads();
    m = fmaxf(fmaxf(red[0], red[1]), fmaxf(red[2], red[3]));

    float sum = 0.f;
    for (int j = tid; j <= q; j += 256) { float e = __expf(buf[j] - m); buf[j] = e; sum += e; }
#pragma unroll
    for (int o = 32; o > 0; o >>= 1) sum += __shfl_xor(sum, o);
    if ((tid & 63) == 0) red[4 + (tid >> 6)] = sum;
    __syncthreads();
    const float inv = 1.f / (red[4] + red[5] + red[6] + red[7]);

    __hip_bfloat162* p2 = (__hip_bfloat162*)srow;
    for (int i = tid; i < N / 2; i += 256) {
        int j0 = i * 2;
        __hip_bfloat162 h;
        h.x = __float2bfloat16(j0     <= q ? buf[j0]     * inv : 0.f);
        h.y = __float2bfloat16(j0 + 1 <= q ? buf[j0 + 1] * inv : 0.f);
        p2[i] = h;
    }
}

__global__ void transpose_bf16(const __hip_bfloat16* __restrict__ V,
                               __hip_bfloat16* __restrict__ Vt, int N)
{
    __shared__ __hip_bfloat16 tile[32][33];
    const size_t bo = (size_t)blockIdx.z * N * N;
    const int k0 = blockIdx.x * 32, d0 = blockIdx.y * 32;
    const int tx = threadIdx.x, ty = threadIdx.y;   // 32 x 8
#pragma unroll
    for (int j = 0; j < 4; ++j)
        tile[ty + 8 * j][tx] = V[bo + (size_t)(k0 + ty + 8 * j) * N + d0 + tx];
    __syncthreads();
#pragma unroll
    for (int j = 0; j < 4; ++j)
        Vt[bo + (size_t)(d0 + ty + 8 * j) * N + k0 + tx] = tile[tx][ty + 8 * j];
}

// ---------------------------------------------------------------------------
extern "C" void kernel_launch(void* const* d_in, const int* in_sizes, int n_in,
                              void* d_out, int out_size, void* d_ws, size_t ws_size,
                              hipStream_t stream)
{
    const float* x  = (const float*)d_in[0];
    const int* pos  = (const int*)d_in[1];
    const float* wq = (const float*)d_in[2];
    const float* wk = (const float*)d_in[3];
    const float* wv = (const float*)d_in[4];
    const float* wo = (const float*)d_in[5];
    float* out = (float*)d_out;

    const int B = 4, N = 2048, D = 2048;
    const int M = B * N;                      // 8192
    const size_t MB = 1ull << 20;
    if (ws_size < 192 * MB) return;

    char* w = (char*)d_ws;
    __hip_bfloat16* Qb  = (__hip_bfloat16*)(w + 0 * MB);
    __hip_bfloat16* Kb  = (__hip_bfloat16*)(w + 32 * MB);
    __hip_bfloat16* Vb  = (__hip_bfloat16*)(w + 64 * MB);
    __hip_bfloat16* wqb = (__hip_bfloat16*)(w + 96 * MB);
    __hip_bfloat16* wkb = (__hip_bfloat16*)(w + 104 * MB);
    __hip_bfloat16* wvb = (__hip_bfloat16*)(w + 112 * MB);
    __hip_bfloat16* wob = (__hip_bfloat16*)(w + 120 * MB);
    __hip_bfloat16* xb  = (__hip_bfloat16*)(w + 128 * MB);  // dead after projections
    __hip_bfloat16* Vt  = xb;                                // alias
    __hip_bfloat16* AO  = (__hip_bfloat16*)(w + 160 * MB);
    float2*         tab = (float2*)(w + 190 * MB);           // 1 MiB

    float* Sal = (float*)d_out;              // S for all 4 batches = 64MB = d_out

    // 1. convert to bf16 (x + 4 weights in 2 dispatches)
    f32_to_bf16_vec<<<(M * D / 4 + 255) / 256, 256, 0, stream>>>(x, xb, M * D / 4);
    conv_w4<<<dim3((D * D / 4 + 255) / 256, 4), 256, 0, stream>>>(
        wq, wk, wv, wo, wqb, wkb, wvb, wob, D * D / 4);
    rope_table<<<(N * 64 + 255) / 256, 256, 0, stream>>>(pos, tab, N);

    // 2. projections: grid 8x32 = 256 wgs
    const int nbxP = D / 256;
    dim3 gp((D / 256) * (M / 256), 1);
    gemm256<__hip_bfloat16, false, false><<<gp, 512, 0, stream>>>(xb, wqb, Qb, D, D, D, D, nbxP, 1.f, 0, 0, 0);
    gemm256<__hip_bfloat16, false, false><<<gp, 512, 0, stream>>>(xb, wkb, Kb, D, D, D, D, nbxP, 1.f, 0, 0, 0);
    gemm256<__hip_bfloat16, false, false><<<gp, 512, 0, stream>>>(xb, wvb, Vb, D, D, D, D, nbxP, 1.f, 0, 0, 0);

    // 3. RoPE on Q and K (one dispatch)
    rope_apply2<<<dim3(M * 256 / 256, 2), 256, 0, stream>>>(Qb, Kb, tab);

    // 4. V transpose (Vt aliases dead xb)
    transpose_bf16<<<dim3(N / 32, N / 32, B), dim3(32, 8), 0, stream>>>(Vb, Vt, N);

    // 5. attention, all batches per dispatch
    const float scale = 1.0f / sqrtf((float)D);
    const int nbxA = N / 256;
    dim3 ga(nbxA * (N / 256), B);
    gemm256<float, true, false><<<ga, 512, 0, stream>>>(
        Qb, Kb, Sal, D, D, D, N, nbxA, scale, (size_t)N * D, (size_t)N * D, (size_t)N * N);
    softmax_causal_ip<<<dim3(N, B), 256, 0, stream>>>(Sal, N);
    gemm256<__hip_bfloat16, false, true><<<ga, 512, 0, stream>>>(
        (const __hip_bfloat16*)Sal, Vt, AO, N, 2 * N, D, D, nbxA, 1.f,
        (size_t)2 * N * N, (size_t)N * D, (size_t)N * D);

    // 6. output projection (fp32, overwrites all of d_out)
    gemm256<float, false, false><<<gp, 512, 0, stream>>>(AO, wob, out, D, D, D, D, nbxP, 1.f, 0, 0, 0);
}

// Round 4
// 479.585 us; speedup vs baseline: 1.0257x; 1.0257x over previous
//
#include <hip/hip_runtime.h>
#include <hip/hip_bf16.h>
#include <cstdint>
#include <cmath>

typedef __attribute__((ext_vector_type(4))) float f32x4;
typedef __attribute__((ext_vector_type(8))) short bf16x8;

#define BAR()   __builtin_amdgcn_s_barrier()
#define PRIO1() __builtin_amdgcn_s_setprio(1)
#define PRIO0() __builtin_amdgcn_s_setprio(0)
#define WAITV4() asm volatile("s_waitcnt vmcnt(4)" ::: "memory")
#define WAITV0() asm volatile("s_waitcnt vmcnt(0)" ::: "memory")
#define MM(a,b,c) __builtin_amdgcn_mfma_f32_16x16x32_bf16((a),(b),(c),0,0,0)

__device__ __forceinline__ void gl_lds16(const __hip_bfloat16* g, char* l) {
    __builtin_amdgcn_global_load_lds(
        (const __attribute__((address_space(1))) void*)g,
        (__attribute__((address_space(3))) void*)l, 16, 0, 0);
}
__device__ __forceinline__ void store_c(float* C, size_t i, float v) { C[i] = v; }
__device__ __forceinline__ void store_c(__hip_bfloat16* C, size_t i, float v) { C[i] = __float2bfloat16(v); }

// ---------------------------------------------------------------------------
// 256x256-tile GEMM, BK=32, 8 waves (2Mx4N, wave tile 128x64), 3-buffer LDS
// (96KB), 2-tile-deep prefetch, counted vmcnt(4) at tile boundary.
// MODE 0: dense grid, bijective XCD swizzle (projections / out-proj).
// MODE 1: causal S-GEMM — triangular block enumeration (grid = 36/batch);
//         every live block has full K work -> even XCD load.
// MODE 2: PV GEMM — kend = bm0+256 (P zero above diagonal); diagonal-shifted
//         (bx = g%nbx, by = (g/nbx + bx)%nby) so each XCD sees every row once
//         (balanced K-work) and a single B panel (L2 locality).
// LDS tile: 16 subtiles of 16rx32c bf16 (1024B), inner byte (r&15)*64 + c*2,
// XOR-swizzled bit5 ^= bit9; linear global_load_lds dest + inverse-swizzled
// per-lane global source; ds_read uses the same swizzle (R1/R3-proven).
// ---------------------------------------------------------------------------
#define STAGEA(nb, kt) do{ gl_lds16(Asrc + (kt),                        lds + (nb)         + wb); \
                           gl_lds16(Asrc + (size_t)128 * lda + (kt),    lds + (nb) +  8192 + wb);}while(0)
#define STAGEB(nb, kt) do{ gl_lds16(Bsrc + (kt),                        lds + (nb) + 16384 + wb); \
                           gl_lds16(Bsrc + (size_t)128 * ldb + (kt),    lds + (nb) + 24576 + wb);}while(0)

template<typename CT, int MODE>
__global__ __launch_bounds__(512, 2)
void gemm256(const __hip_bfloat16* __restrict__ A, const __hip_bfloat16* __restrict__ B,
             CT* __restrict__ C, int K, int lda, int ldb, int ldc, int nbx,
             float alpha, size_t sA, size_t sB, size_t sC)
{
    __shared__ __align__(1024) char lds[98304];

    int bm0, bn0;
    if (MODE == 1) {
        const int wg = blockIdx.x;
        int by = (int)((sqrtf(8.f * wg + 1.f) - 1.f) * 0.5f);
        if (by * (by + 1) / 2 > wg) --by;                 // fp guard
        if ((by + 1) * (by + 2) / 2 <= wg) ++by;
        const int bx = wg - by * (by + 1) / 2;
        bm0 = by * 256; bn0 = bx * 256;
    } else if (MODE == 2) {
        const int g = blockIdx.x;
        const int nby = gridDim.x / nbx;
        const int bx = g % nbx;
        const int by = (g / nbx + bx) % nby;
        bm0 = by * 256; bn0 = bx * 256;
    } else {
        // bijective XCD-aware swizzle (m204)
        const int nwg = gridDim.x;
        const int q8 = nwg >> 3, r8 = nwg & 7;
        const int xcd = blockIdx.x & 7, blk = blockIdx.x >> 3;
        const int wg = (xcd < r8 ? xcd * (q8 + 1) : r8 * (q8 + 1) + (xcd - r8) * q8) + blk;
        bm0 = (wg / nbx) * 256; bn0 = (wg % nbx) * 256;
    }

    A += sA * blockIdx.y; B += sB * blockIdx.y; C += sC * blockIdx.y;

    const int tid  = threadIdx.x;
    const int lane = tid & 63;
    const int w    = tid >> 6;
    const int wb   = w * 1024;

    // ds_read per-lane swizzled inner offset (fr = lane&15, k-sub = lane>>4)
    const int rb   = (lane & 15) * 64 + (lane >> 4) * 16;
    const int rswz = rb ^ (((rb >> 9) & 1) << 5);
    const int srA  = (w >> 2) * 8;      // A subtile base; +mi
    const int srB  = (w & 3) * 4;       // B subtile base; +ni

    // staging: invert swizzled layout for this thread's linear LDS chunk
    const int q0 = tid * 16;
    const int uq = q0 ^ (((q0 >> 9) & 1) << 5);
    const int r0 = ((q0 >> 10) << 4) | ((uq >> 6) & 15);
    const int c0 = (uq & 63) >> 1;
    const __hip_bfloat16* Asrc = A + (size_t)(bm0 + r0) * lda + c0;
    const __hip_bfloat16* Bsrc = B + (size_t)(bn0 + r0) * ldb + c0;

    f32x4 acc[8][4] = {};
    bf16x8 af[4], bf[4];

    const int klim = bm0 + 256;
    const int kend = (MODE == 2) ? (K < klim ? K : klim) : K;
    const int nt   = kend >> 5;

    // prologue: tile0 -> buf0, tile1 -> buf1
    STAGEA(0, 0); STAGEB(0, 0);
    if (nt > 1) { STAGEA(32768, 32); STAGEB(32768, 32); }

    for (int t = 0; t < nt; ++t) {
        if (t + 1 < nt) WAITV4(); else WAITV0();
        BAR();
        const char* dA = lds + (t % 3) * 32768;
        const char* dB = dA + 16384;
        const int  nbo = ((t + 2) % 3) * 32768;
        const bool pf  = (t + 2 < nt);
        const int  kt  = (t + 2) << 5;

        // ---- phase 0: A mi0-3 + B all; MFMA upper half ----
#pragma unroll
        for (int i = 0; i < 4; ++i) af[i] = *(const bf16x8*)(dA + ((srA + i) << 10) + rswz);
#pragma unroll
        for (int i = 0; i < 4; ++i) bf[i] = *(const bf16x8*)(dB + ((srB + i) << 10) + rswz);
        if (pf) STAGEA(nbo, kt);
        BAR();
        PRIO1();
#pragma unroll
        for (int mi = 0; mi < 4; ++mi)
#pragma unroll
            for (int ni = 0; ni < 4; ++ni)
                acc[mi][ni] = MM(af[mi], bf[ni], acc[mi][ni]);
        PRIO0();

        // ---- phase 1: A mi4-7 (B reused); MFMA lower half ----
#pragma unroll
        for (int i = 0; i < 4; ++i) af[i] = *(const bf16x8*)(dA + ((srA + 4 + i) << 10) + rswz);
        if (pf) STAGEB(nbo, kt);
        BAR();
        PRIO1();
#pragma unroll
        for (int mi = 0; mi < 4; ++mi)
#pragma unroll
            for (int ni = 0; ni < 4; ++ni)
                acc[4 + mi][ni] = MM(af[mi], bf[ni], acc[4 + mi][ni]);
        PRIO0();
    }

    // epilogue: C/D layout col=lane&15, row=(lane>>4)*4+j (m89/m91)
    const int cr = (lane >> 4) * 4, cc = lane & 15;
    const int wrow = bm0 + (w >> 2) * 128, wcol = bn0 + (w & 3) * 64;
#pragma unroll
    for (int mi = 0; mi < 8; ++mi)
#pragma unroll
        for (int ni = 0; ni < 4; ++ni) {
            const int row = wrow + mi * 16 + cr;
            const int col = wcol + ni * 16 + cc;
#pragma unroll
            for (int j = 0; j < 4; ++j)
                store_c(C, (size_t)(row + j) * ldc + col, acc[mi][ni][j] * alpha);
        }
}

// ---------------------------------------------------------------------------
__global__ void f32_to_bf16_vec(const float* __restrict__ in,
                                __hip_bfloat16* __restrict__ out, int n4)
{
    int i = blockIdx.x * 256 + threadIdx.x;
    if (i >= n4) return;
    float4 v = ((const float4*)in)[i];
    union { ushort4 u; __hip_bfloat16 h[4]; } o;
    o.h[0] = __float2bfloat16(v.x);
    o.h[1] = __float2bfloat16(v.y);
    o.h[2] = __float2bfloat16(v.z);
    o.h[3] = __float2bfloat16(v.w);
    ((ushort4*)out)[i] = o.u;
}

// 4 same-size weight matrices in one dispatch (blockIdx.y selects)
__global__ void conv_w4(const float* __restrict__ w0, const float* __restrict__ w1,
                        const float* __restrict__ w2, const float* __restrict__ w3,
                        __hip_bfloat16* o0, __hip_bfloat16* o1,
                        __hip_bfloat16* o2, __hip_bfloat16* o3, int n4)
{
    int i = blockIdx.x * 256 + threadIdx.x;
    if (i >= n4) return;
    const float* src; __hip_bfloat16* dst;
    switch (blockIdx.y) {
        case 0: src = w0; dst = o0; break;
        case 1: src = w1; dst = o1; break;
        case 2: src = w2; dst = o2; break;
        default: src = w3; dst = o3; break;
    }
    float4 v = ((const float4*)src)[i];
    union { ushort4 u; __hip_bfloat16 h[4]; } o;
    o.h[0] = __float2bfloat16(v.x);
    o.h[1] = __float2bfloat16(v.y);
    o.h[2] = __float2bfloat16(v.z);
    o.h[3] = __float2bfloat16(v.w);
    ((ushort4*)dst)[i] = o.u;
}

__global__ void rope_table(const int* __restrict__ pos, float2* __restrict__ tab, int N)
{
    int i = blockIdx.x * 256 + threadIdx.x;
    if (i >= N * 64) return;
    int n = i >> 6, j = i & 63;
    float p = (float)pos[n];
    float ang = p * powf(10000.f, -(float)j * (1.0f / 64.0f));
    tab[i] = make_float2(cosf(ang), sinf(ang));
}

// RoPE on Q and K in one dispatch, 16B vectorized (4 interleaved pairs/thread)
__global__ void rope_apply2(__hip_bfloat16* __restrict__ Q, __hip_bfloat16* __restrict__ K,
                            const float2* __restrict__ tab)
{
    int i = blockIdx.x * 256 + threadIdx.x;     // 8192 rows x 256 chunks
    __hip_bfloat16* T = blockIdx.y ? K : Q;
    int r  = i >> 8;
    int cb = (i & 255) << 3;                    // col base: 8 cols = 4 pairs
    int n  = r & 2047;
    int j0 = (cb >> 1) & 63;                    // pair idx within head (j0%4==0)
    union { bf16x8 v; __hip_bfloat162 h[4]; } u;
    __hip_bfloat16* p = T + ((size_t)r << 11) + cb;
    u.v = *(const bf16x8*)p;
#pragma unroll
    for (int k = 0; k < 4; ++k) {
        float2 cs = tab[(n << 6) + j0 + k];
        float x1 = __bfloat162float(u.h[k].x);
        float x2 = __bfloat162float(u.h[k].y);
        u.h[k].x = __float2bfloat16(cs.x * x1 - cs.y * x2);
        u.h[k].y = __float2bfloat16(cs.y * x1 + cs.x * x2);
    }
    *(bf16x8*)p = u.v;
}

// ---------------------------------------------------------------------------
// In-place causal softmax: fp32 row q of S -> bf16 P over the same row
// (row stride stays 8KB = 4096 bf16 elements). Row staged in LDS.
// ---------------------------------------------------------------------------
__global__ void softmax_causal_ip(float* __restrict__ S, int N)
{
    const int q = blockIdx.x;
    float* srow = S + ((size_t)blockIdx.y * N + q) * N;
    __shared__ float buf[2048];
    __shared__ float red[8];
    const int tid = threadIdx.x;

    float4* b4 = (float4*)buf;
    const float4* s4 = (const float4*)srow;
    for (int i = tid; i < N / 4; i += 256) b4[i] = s4[i];
    __syncthreads();

    float m = -1e30f;
    for (int j = tid; j <= q; j += 256) m = fmaxf(m, buf[j]);
#pragma unroll
    for (int o = 32; o > 0; o >>= 1) m = fmaxf(m, __shfl_xor(m, o));
    if ((tid & 63) == 0) red[tid >> 6] = m;
    __syncthreads();
    m = fmaxf(fmaxf(red[0], red[1]), fmaxf(red[2], red[3]));

    float sum = 0.f;
    for (int j = tid; j <= q; j += 256) { float e = __expf(buf[j] - m); buf[j] = e; sum += e; }
#pragma unroll
    for (int o = 32; o > 0; o >>= 1) sum += __shfl_xor(sum, o);
    if ((tid & 63) == 0) red[4 + (tid >> 6)] = sum;
    __syncthreads();
    const float inv = 1.f / (red[4] + red[5] + red[6] + red[7]);

    __hip_bfloat162* p2 = (__hip_bfloat162*)srow;
    for (int i = tid; i < N / 2; i += 256) {
        int j0 = i * 2;
        __hip_bfloat162 h;
        h.x = __float2bfloat16(j0     <= q ? buf[j0]     * inv : 0.f);
        h.y = __float2bfloat16(j0 + 1 <= q ? buf[j0 + 1] * inv : 0.f);
        p2[i] = h;
    }
}

__global__ void transpose_bf16(const __hip_bfloat16* __restrict__ V,
                               __hip_bfloat16* __restrict__ Vt, int N)
{
    __shared__ __hip_bfloat16 tile[32][33];
    const size_t bo = (size_t)blockIdx.z * N * N;
    const int k0 = blockIdx.x * 32, d0 = blockIdx.y * 32;
    const int tx = threadIdx.x, ty = threadIdx.y;   // 32 x 8
#pragma unroll
    for (int j = 0; j < 4; ++j)
        tile[ty + 8 * j][tx] = V[bo + (size_t)(k0 + ty + 8 * j) * N + d0 + tx];
    __syncthreads();
#pragma unroll
    for (int j = 0; j < 4; ++j)
        Vt[bo + (size_t)(d0 + ty + 8 * j) * N + k0 + tx] = tile[tx][ty + 8 * j];
}

// ---------------------------------------------------------------------------
extern "C" void kernel_launch(void* const* d_in, const int* in_sizes, int n_in,
                              void* d_out, int out_size, void* d_ws, size_t ws_size,
                              hipStream_t stream)
{
    const float* x  = (const float*)d_in[0];
    const int* pos  = (const int*)d_in[1];
    const float* wq = (const float*)d_in[2];
    const float* wk = (const float*)d_in[3];
    const float* wv = (const float*)d_in[4];
    const float* wo = (const float*)d_in[5];
    float* out = (float*)d_out;

    const int B = 4, N = 2048, D = 2048;
    const int M = B * N;                      // 8192
    const size_t MB = 1ull << 20;
    if (ws_size < 192 * MB) return;

    char* w = (char*)d_ws;
    __hip_bfloat16* Qb  = (__hip_bfloat16*)(w + 0 * MB);
    __hip_bfloat16* Kb  = (__hip_bfloat16*)(w + 32 * MB);
    __hip_bfloat16* Vb  = (__hip_bfloat16*)(w + 64 * MB);
    __hip_bfloat16* wqb = (__hip_bfloat16*)(w + 96 * MB);
    __hip_bfloat16* wkb = (__hip_bfloat16*)(w + 104 * MB);
    __hip_bfloat16* wvb = (__hip_bfloat16*)(w + 112 * MB);
    __hip_bfloat16* wob = (__hip_bfloat16*)(w + 120 * MB);
    __hip_bfloat16* xb  = (__hip_bfloat16*)(w + 128 * MB);  // dead after projections
    __hip_bfloat16* Vt  = xb;                                // alias
    __hip_bfloat16* AO  = (__hip_bfloat16*)(w + 160 * MB);
    float2*         tab = (float2*)(w + 190 * MB);           // 1 MiB

    float* Sal = (float*)d_out;              // S for all 4 batches = 64MB = d_out

    // 1. convert to bf16 (x + 4 weights), RoPE table
    f32_to_bf16_vec<<<(M * D / 4 + 255) / 256, 256, 0, stream>>>(x, xb, M * D / 4);
    conv_w4<<<dim3((D * D / 4 + 255) / 256, 4), 256, 0, stream>>>(
        wq, wk, wv, wo, wqb, wkb, wvb, wob, D * D / 4);
    rope_table<<<(N * 64 + 255) / 256, 256, 0, stream>>>(pos, tab, N);

    // 2. projections: grid 8x32 = 256 wgs
    const int nbxP = D / 256;
    dim3 gp((D / 256) * (M / 256), 1);
    gemm256<__hip_bfloat16, 0><<<gp, 512, 0, stream>>>(xb, wqb, Qb, D, D, D, D, nbxP, 1.f, 0, 0, 0);
    gemm256<__hip_bfloat16, 0><<<gp, 512, 0, stream>>>(xb, wkb, Kb, D, D, D, D, nbxP, 1.f, 0, 0, 0);
    gemm256<__hip_bfloat16, 0><<<gp, 512, 0, stream>>>(xb, wvb, Vb, D, D, D, D, nbxP, 1.f, 0, 0, 0);

    // 3. RoPE on Q and K (one dispatch)
    rope_apply2<<<dim3(M * 256 / 256, 2), 256, 0, stream>>>(Qb, Kb, tab);

    // 4. V transpose (Vt aliases dead xb)
    transpose_bf16<<<dim3(N / 32, N / 32, B), dim3(32, 8), 0, stream>>>(Vb, Vt, N);

    // 5. attention, all batches per dispatch
    const float scale = 1.0f / sqrtf((float)D);
    const int nbxA = N / 256;                           // 8
    const int ntri = nbxA * (nbxA + 1) / 2;             // 36
    gemm256<float, 1><<<dim3(ntri, B), 512, 0, stream>>>(
        Qb, Kb, Sal, D, D, D, N, nbxA, scale, (size_t)N * D, (size_t)N * D, (size_t)N * N);
    softmax_causal_ip<<<dim3(N, B), 256, 0, stream>>>(Sal, N);
    gemm256<__hip_bfloat16, 2><<<dim3(nbxA * nbxA, B), 512, 0, stream>>>(
        (const __hip_bfloat16*)Sal, Vt, AO, N, 2 * N, D, D, nbxA, 1.f,
        (size_t)2 * N * N, (size_t)N * D, (size_t)N * D);

    // 6. output projection (fp32, overwrites all of d_out)
    gemm256<float, 0><<<gp, 512, 0, stream>>>(AO, wob, out, D, D, D, D, nbxP, 1.f, 0, 0, 0);
}